// Round 4
// baseline (2051.976 us; speedup 1.0000x reference)
//
#include <hip/hip_runtime.h>
#include <hip/hip_fp16.h>

#define NN 20000
#define NE 300000
#define NT 500000
#define HD 128
#define NRR 6
#define NSNRD 42
#define NBB 8

using f16x8 = __attribute__((ext_vector_type(8))) _Float16;
using f32x4 = __attribute__((ext_vector_type(4))) float;

__device__ __forceinline__ float silu_f(float v){ return v / (1.f + __expf(-v)); }

// ---- W_bil [i][jb][l] -> WB2 fp16 [jb][i][l]  (B^T layout for MFMA frags) ----
__global__ void k_wb2(const float* __restrict__ Wb, __half* __restrict__ WB2){
  int idx = blockIdx.x*256 + threadIdx.x;     // 131072 total
  int l = idx & 127, i = (idx>>7) & 127, jb = idx>>14;
  WB2[jb*16384 + i*128 + l] = __float2half(Wb[i*1024 + jb*128 + l]);
}

// ---- W_kj/W_ji/W_lin [k][i] -> fp16 transposed [i][k] ----
__global__ void k_wT(const float* __restrict__ Wkj, const float* __restrict__ Wji,
                     const float* __restrict__ Wlin, __half* __restrict__ WkjT,
                     __half* __restrict__ WjiT, __half* __restrict__ WlinT){
  int idx = blockIdx.x*256 + threadIdx.x;     // 49152 total
  int which = idx>>14, rem = idx & 16383;
  int i = rem>>7, k = rem & 127;
  const float* src = which==0 ? Wkj : (which==1 ? Wji : Wlin);
  __half* dst = which==0 ? WkjT : (which==1 ? WjiT : WlinT);
  dst[rem] = __float2half(src[k*HD + i]);
}

// ================= k_edge_pre =================
// xkj = fp16( silu(x@W_kj+b_kj) * (rbf@W_rbf) ), fused block-0 gate scatter.
#define EROWS 128
#define PRE_A 0
#define PRE_B 32768
#define PRE_RBF 65536
#define PRE_WR 68608
#define PRE_LS 71680
#define PRE_NID 74752
#define SH_PRE 75264
__global__ __launch_bounds__(256,2)
void k_edge_pre(const float* __restrict__ x, const float* __restrict__ rbf,
                const int* __restrict__ nid, const __half* __restrict__ WkjT,
                const float* __restrict__ bkj, const float* __restrict__ Wrbf,
                const float* __restrict__ lrbf0, __half* __restrict__ xkj,
                float* __restrict__ g0){
  extern __shared__ char sm[];
  int tid = threadIdx.x;
  long e0 = (long)blockIdx.x * EROWS;
  // B^T = WkjT [i][k] fp16, swizzled
  for(int c=tid;c<2048;c+=256){
    int i=c>>4, cc=c&15;
    float4 v = *(const float4*)(WkjT + i*128 + cc*8);
    *(float4*)(sm + PRE_B + ((i*256+cc*16)^((i&7)<<4))) = v;
  }
  // A = fp16(x rows), swizzled
  for(int c=tid;c<2048;c+=256){
    int r=c>>4, cc=c&15; long e=e0+r;
    __half h8[8];
    if(e<NE){
      const float* px = x + e*HD + cc*8;
      #pragma unroll
      for(int j=0;j<8;j++) h8[j]=__float2half(px[j]);
    } else {
      #pragma unroll
      for(int j=0;j<8;j++) h8[j]=__float2half(0.f);
    }
    *(float4*)(sm + PRE_A + ((r*256+cc*16)^((r&7)<<4))) = *(float4*)h8;
  }
  float* rbft=(float*)(sm+PRE_RBF);
  for(int q=tid;q<EROWS*NRR;q+=256){ long e=e0+q/NRR; rbft[q]=(e<NE)? rbf[e*NRR + q%NRR] : 0.f; }
  float* wrbf=(float*)(sm+PRE_WR);
  for(int q=tid;q<NRR*HD;q+=256) wrbf[q]=Wrbf[q];
  float* ls0=(float*)(sm+PRE_LS);
  for(int q=tid;q<NRR*HD;q+=256) ls0[q]=lrbf0[q];
  int* nids=(int*)(sm+PRE_NID);
  for(int q=tid;q<EROWS;q+=256){ long e=e0+q; nids[q]=(e<NE)? nid[e] : 0; }
  __syncthreads();
  int lane=tid&63, wv=tid>>6;
  f16x8 af[2][4];
  #pragma unroll
  for(int rt=0;rt<2;rt++){
    int r = wv*32 + rt*16 + (lane&15);
    #pragma unroll
    for(int ks=0;ks<4;ks++)
      af[rt][ks] = *(const f16x8*)(sm + PRE_A + ((r*256 + (ks*4+(lane>>4))*16)^((r&7)<<4)));
  }
  f32x4 acc[2][8];
  #pragma unroll
  for(int rt=0;rt<2;rt++){
    #pragma unroll
    for(int ct=0;ct<8;ct++) acc[rt][ct]=(f32x4){0.f,0.f,0.f,0.f};
  }
  #pragma unroll
  for(int ct=0;ct<8;ct++){
    int i = ct*16 + (lane&15);
    #pragma unroll
    for(int ks=0;ks<4;ks++){
      f16x8 b = *(const f16x8*)(sm + PRE_B + ((i*256 + (ks*4+(lane>>4))*16)^((i&7)<<4)));
      acc[0][ct] = __builtin_amdgcn_mfma_f32_16x16x32_f16(af[0][ks], b, acc[0][ct], 0,0,0);
      acc[1][ct] = __builtin_amdgcn_mfma_f32_16x16x32_f16(af[1][ks], b, acc[1][ct], 0,0,0);
    }
  }
  #pragma unroll
  for(int rt=0;rt<2;rt++){
    #pragma unroll
    for(int j=0;j<4;j++){
      int rloc = wv*32 + rt*16 + (lane>>4)*4 + j;
      long e = e0 + rloc;
      if(e<NE){
        #pragma unroll
        for(int ct=0;ct<8;ct++){
          int h = ct*16 + (lane&15);
          float v = silu_f(acc[rt][ct][j] + bkj[h]);
          float r2 = 0.f;
          #pragma unroll
          for(int q=0;q<NRR;q++) r2 += rbft[rloc*NRR+q]*wrbf[q*HD+h];
          xkj[e*HD + h] = __float2half(v*r2);
        }
      }
    }
  }
  // block-0 gate scatter: g0[nid[e]] += (rbf@lrbf0)*x[e]  (A tile unchanged)
  for(int c=tid;c<2048;c+=256){
    int r=c>>4, cc=c&15; long e=e0+r;
    if(e<NE){
      f16x8 xv = *(const f16x8*)(sm + PRE_A + ((r*256+cc*16)^((r&7)<<4)));
      int nb = nids[r];
      #pragma unroll
      for(int j=0;j<8;j++){
        int h = cc*8 + j;
        float gate = 0.f;
        #pragma unroll
        for(int q=0;q<NRR;q++) gate += rbft[r*NRR+q]*ls0[q*HD+h];
        atomicAdd(&g0[(long)nb*HD + h], gate*(float)xv[j]);
      }
    }
  }
}

// ================= k_triplet_mfma =================
// t[w,i] = sum_jb sp[w,jb]*(xg[w,:]@W_bil[:,jb,:]^T)[i]; sp computed in-kernel.
#define TROWS 128
#define OFF_BS 0
#define OFF_XG 32768
#define OFF_SP 65536
#define OFF_JI 69632
#define OFF_KJ 70144
#define OFF_WSB 70656
#define SH_TRIP 72000
__global__ __launch_bounds__(256,2)
void k_triplet_mfma(const __half* __restrict__ xkj, const float* __restrict__ sbf,
                    const float* __restrict__ Wsbf,
                    const int* __restrict__ ikj, const int* __restrict__ iji,
                    const __half* __restrict__ WB2, float* __restrict__ agg){
  extern __shared__ char sm[];
  int tid = threadIdx.x;
  long t0 = (long)blockIdx.x * TROWS;
  int* kjs = (int*)(sm + OFF_KJ);
  int* jis = (int*)(sm + OFF_JI);
  if (tid < TROWS){
    int ok = (t0 + tid) < NT;
    kjs[tid] = ok ? ikj[t0+tid] : 0;
    jis[tid] = ok ? iji[t0+tid] : -1;
  }
  // sbf tile into (future) Bs region; Wsbf
  float* sbuf = (float*)(sm + OFF_BS);
  for(int q=tid;q<TROWS*NSNRD;q+=256){
    long t = t0 + q/NSNRD;
    sbuf[q] = (t<NT) ? sbf[t*NSNRD + q%NSNRD] : 0.f;
  }
  float* wsb = (float*)(sm + OFF_WSB);
  for(int q=tid;q<NSNRD*NBB;q+=256) wsb[q]=Wsbf[q];
  __syncthreads();   // kjs, sbuf, wsb ready
  // gather xg rows (fp16, swizzled)
  for(int c=tid;c<TROWS*16;c+=256){
    int w = c>>4, cc = c&15;
    float4 v = *(const float4*)(xkj + (long)kjs[w]*HD + cc*8);
    *(float4*)(sm + OFF_XG + ((w*256 + cc*16)^((w&7)<<4))) = v;
  }
  // spl[r][8] = sbuf[r,:] @ Wsbf
  float* spl = (float*)(sm + OFF_SP);
  {
    int r = tid>>1, j0 = (tid&1)*4;
    float a0=0.f,a1=0.f,a2=0.f,a3=0.f;
    for(int q=0;q<NSNRD;q++){
      float v = sbuf[r*NSNRD+q];
      a0 += v*wsb[q*NBB+j0];   a1 += v*wsb[q*NBB+j0+1];
      a2 += v*wsb[q*NBB+j0+2]; a3 += v*wsb[q*NBB+j0+3];
    }
    spl[r*NBB+j0]=a0; spl[r*NBB+j0+1]=a1; spl[r*NBB+j0+2]=a2; spl[r*NBB+j0+3]=a3;
  }
  __syncthreads();   // xg, spl ready
  int lane = tid & 63, wvid = tid >> 6;
  float spreg[2][NBB];
  #pragma unroll
  for(int rt=0;rt<2;rt++){
    int w = wvid*32 + rt*16 + (lane&15);
    #pragma unroll
    for(int jb=0;jb<NBB;jb++) spreg[rt][jb] = spl[w*NBB + jb];
  }
  f16x8 au[2][4];
  #pragma unroll
  for(int rt=0;rt<2;rt++){
    int w = wvid*32 + rt*16 + (lane&15);
    #pragma unroll
    for(int ks=0;ks<4;ks++)
      au[rt][ks] = *(const f16x8*)(sm + OFF_XG + ((w*256 + ks*64 + (lane>>4)*16)^((w&7)<<4)));
  }
  f32x4 acc[2][8];
  #pragma unroll
  for(int rt=0;rt<2;rt++){
    #pragma unroll
    for(int ct=0;ct<8;ct++) acc[rt][ct] = (f32x4){0.f,0.f,0.f,0.f};
  }
  for(int jb=0;jb<NBB;jb++){
    __syncthreads();   // prior Bs/sbuf reads done
    for(int c=tid;c<2048;c+=256){
      int i = c>>4, lc = c&15;
      float4 v = *(const float4*)(WB2 + jb*16384 + i*128 + lc*8);
      *(float4*)(sm + OFF_BS + ((i*256 + lc*16)^((i&7)<<4))) = v;
    }
    __syncthreads();
    f16x8 as[2][4];
    #pragma unroll
    for(int rt=0;rt<2;rt++){
      _Float16 s = (_Float16)spreg[rt][jb];
      #pragma unroll
      for(int ks=0;ks<4;ks++){
        #pragma unroll
        for(int j=0;j<8;j++) as[rt][ks][j] = au[rt][ks][j] * s;
      }
    }
    #pragma unroll
    for(int ct=0;ct<8;ct++){
      int i = ct*16 + (lane&15);
      int obase = i*256 + (lane>>4)*16;
      #pragma unroll
      for(int ks=0;ks<4;ks++){
        f16x8 b = *(const f16x8*)(sm + OFF_BS + ((obase + ks*64)^((i&7)<<4)));
        acc[0][ct] = __builtin_amdgcn_mfma_f32_16x16x32_f16(as[0][ks], b, acc[0][ct], 0,0,0);
        acc[1][ct] = __builtin_amdgcn_mfma_f32_16x16x32_f16(as[1][ks], b, acc[1][ct], 0,0,0);
      }
    }
  }
  #pragma unroll
  for(int rt=0;rt<2;rt++){
    #pragma unroll
    for(int r=0;r<4;r++){
      int w = wvid*32 + rt*16 + (lane>>4)*4 + r;
      int ji = jis[w];
      if (ji >= 0){
        #pragma unroll
        for(int ct=0;ct<8;ct++)
          atomicAdd(&agg[(long)ji*HD + ct*16 + (lane&15)], acc[rt][ct][r]);
      }
    }
  }
}

// ================= k_edge_post =================
// tmp = silu(x@W_ji+b_ji)+agg; x2 = silu(tmp@W_lin+b_lin); g1 scatter of gate1*x2.
#define PO_A 0
#define PO_B 32768
#define PO_RBF 65536
#define PO_LS 68608
#define PO_NID 71680
#define SH_POST 72192
__global__ __launch_bounds__(256,2)
void k_edge_post(const float* __restrict__ x, const float* __restrict__ rbf,
                 const float* __restrict__ agg, const int* __restrict__ nid,
                 const __half* __restrict__ WjiT, const float* __restrict__ bji,
                 const __half* __restrict__ WlinT, const float* __restrict__ blin,
                 const float* __restrict__ lrbf1, float* __restrict__ g1){
  extern __shared__ char sm[];
  int tid = threadIdx.x;
  long e0 = (long)blockIdx.x * EROWS;
  for(int c=tid;c<2048;c+=256){
    int i=c>>4, cc=c&15;
    float4 v = *(const float4*)(WjiT + i*128 + cc*8);
    *(float4*)(sm + PO_B + ((i*256+cc*16)^((i&7)<<4))) = v;
  }
  for(int c=tid;c<2048;c+=256){
    int r=c>>4, cc=c&15; long e=e0+r;
    __half h8[8];
    if(e<NE){
      const float* px = x + e*HD + cc*8;
      #pragma unroll
      for(int j=0;j<8;j++) h8[j]=__float2half(px[j]);
    } else {
      #pragma unroll
      for(int j=0;j<8;j++) h8[j]=__float2half(0.f);
    }
    *(float4*)(sm + PO_A + ((r*256+cc*16)^((r&7)<<4))) = *(float4*)h8;
  }
  float* rbft=(float*)(sm+PO_RBF);
  for(int q=tid;q<EROWS*NRR;q+=256){ long e=e0+q/NRR; rbft[q]=(e<NE)? rbf[e*NRR + q%NRR] : 0.f; }
  float* ls1=(float*)(sm+PO_LS);
  for(int q=tid;q<NRR*HD;q+=256) ls1[q]=lrbf1[q];
  int* nids=(int*)(sm+PO_NID);
  for(int q=tid;q<EROWS;q+=256){ long e=e0+q; nids[q]=(e<NE)? nid[e] : 0; }
  __syncthreads();
  int lane=tid&63, wv=tid>>6;
  f16x8 af[2][4];
  #pragma unroll
  for(int rt=0;rt<2;rt++){
    int r = wv*32 + rt*16 + (lane&15);
    #pragma unroll
    for(int ks=0;ks<4;ks++)
      af[rt][ks] = *(const f16x8*)(sm + PO_A + ((r*256 + (ks*4+(lane>>4))*16)^((r&7)<<4)));
  }
  f32x4 acc[2][8];
  #pragma unroll
  for(int rt=0;rt<2;rt++){
    #pragma unroll
    for(int ct=0;ct<8;ct++) acc[rt][ct]=(f32x4){0.f,0.f,0.f,0.f};
  }
  #pragma unroll
  for(int ct=0;ct<8;ct++){
    int i = ct*16 + (lane&15);
    #pragma unroll
    for(int ks=0;ks<4;ks++){
      f16x8 b = *(const f16x8*)(sm + PO_B + ((i*256 + (ks*4+(lane>>4))*16)^((i&7)<<4)));
      acc[0][ct] = __builtin_amdgcn_mfma_f32_16x16x32_f16(af[0][ks], b, acc[0][ct], 0,0,0);
      acc[1][ct] = __builtin_amdgcn_mfma_f32_16x16x32_f16(af[1][ks], b, acc[1][ct], 0,0,0);
    }
  }
  __syncthreads();   // all A/B LDS reads of GEMM1 complete
  // tmp = silu(acc+bji)+agg -> overwrite A tile (fp16 swizzled scalar writes)
  #pragma unroll
  for(int rt=0;rt<2;rt++){
    #pragma unroll
    for(int j=0;j<4;j++){
      int rloc = wv*32 + rt*16 + (lane>>4)*4 + j;
      long e = e0 + rloc;
      #pragma unroll
      for(int ct=0;ct<8;ct++){
        int h = ct*16 + (lane&15);
        float v = silu_f(acc[rt][ct][j] + bji[h]);
        v += (e<NE) ? agg[e*HD + h] : 0.f;
        int byo = ((rloc*256 + (h>>3)*16)^((rloc&7)<<4)) + (h&7)*2;
        *(__half*)(sm + PO_A + byo) = __float2half(v);
      }
    }
  }
  for(int c=tid;c<2048;c+=256){
    int i=c>>4, cc=c&15;
    float4 v = *(const float4*)(WlinT + i*128 + cc*8);
    *(float4*)(sm + PO_B + ((i*256+cc*16)^((i&7)<<4))) = v;
  }
  __syncthreads();   // tmp + WlinT staged
  f16x8 af2[2][4];
  #pragma unroll
  for(int rt=0;rt<2;rt++){
    int r = wv*32 + rt*16 + (lane&15);
    #pragma unroll
    for(int ks=0;ks<4;ks++)
      af2[rt][ks] = *(const f16x8*)(sm + PO_A + ((r*256 + (ks*4+(lane>>4))*16)^((r&7)<<4)));
  }
  f32x4 acc2[2][8];
  #pragma unroll
  for(int rt=0;rt<2;rt++){
    #pragma unroll
    for(int ct=0;ct<8;ct++) acc2[rt][ct]=(f32x4){0.f,0.f,0.f,0.f};
  }
  #pragma unroll
  for(int ct=0;ct<8;ct++){
    int i = ct*16 + (lane&15);
    #pragma unroll
    for(int ks=0;ks<4;ks++){
      f16x8 b = *(const f16x8*)(sm + PO_B + ((i*256 + (ks*4+(lane>>4))*16)^((i&7)<<4)));
      acc2[0][ct] = __builtin_amdgcn_mfma_f32_16x16x32_f16(af2[0][ks], b, acc2[0][ct], 0,0,0);
      acc2[1][ct] = __builtin_amdgcn_mfma_f32_16x16x32_f16(af2[1][ks], b, acc2[1][ct], 0,0,0);
    }
  }
  #pragma unroll
  for(int rt=0;rt<2;rt++){
    #pragma unroll
    for(int j=0;j<4;j++){
      int rloc = wv*32 + rt*16 + (lane>>4)*4 + j;
      long e = e0 + rloc;
      if(e<NE){
        int nb = nids[rloc];
        #pragma unroll
        for(int ct=0;ct<8;ct++){
          int h = ct*16 + (lane&15);
          float x2 = silu_f(acc2[rt][ct][j] + blin[h]);
          float gate = 0.f;
          #pragma unroll
          for(int q=0;q<NRR;q++) gate += rbft[rloc*NRR+q]*ls1[q*HD+h];
          atomicAdd(&g1[(long)nb*HD + h], gate*x2);
        }
      }
    }
  }
}

// ---- one silu-MLP layer on node features ----
__global__ __launch_bounds__(256,2)
void k_mlp(const float* __restrict__ gin, const float* __restrict__ W,
           const float* __restrict__ b, float* __restrict__ gout){
  extern __shared__ char sm[];
  float* Ws  = (float*)sm;
  __half* xt = (__half*)(sm+65536);
  int tid=threadIdx.x; int r0=blockIdx.x*32;
  for(int q=tid;q<HD*HD;q+=256) Ws[q]=W[q];
  for(int q=tid;q<32*HD;q+=256) xt[q]=__float2half(gin[(long)(r0+(q>>7))*HD + (q&127)]);
  __syncthreads();
  int c0=tid&31, eg=tid>>5;
  float acc[4][4];
  #pragma unroll
  for(int ee=0;ee<4;ee++){
    #pragma unroll
    for(int kk=0;kk<4;kk++) acc[ee][kk]=0.f;
  }
  for(int k=0;k<HD;k++){
    float wv[4], xv[4];
    #pragma unroll
    for(int kk=0;kk<4;kk++) wv[kk]=Ws[k*HD + c0+32*kk];
    #pragma unroll
    for(int ee=0;ee<4;ee++) xv[ee]=__half2float(xt[(eg*4+ee)*HD + k]);
    #pragma unroll
    for(int ee=0;ee<4;ee++){
      #pragma unroll
      for(int kk=0;kk<4;kk++) acc[ee][kk] += xv[ee]*wv[kk];
    }
  }
  #pragma unroll
  for(int ee=0;ee<4;ee++){
    #pragma unroll
    for(int kk=0;kk<4;kk++)
      gout[(long)(r0+eg*4+ee)*HD + c0+32*kk] = silu_f(acc[ee][kk] + b[c0+32*kk]);
  }
}

// ---- column-sum over nodes ----
__global__ void k_colsum(const float* __restrict__ gin, float* __restrict__ s){
  int tid=threadIdx.x; int h=tid&127;
  float acc=0.f;
  for(int r = blockIdx.x*2 + (tid>>7); r < NN; r += 512) acc += gin[(long)r*HD + h];
  atomicAdd(&s[h], acc);
}

// ---- final readout ----
__global__ void k_readout(const float* __restrict__ s0, const float* __restrict__ s1,
                          const float* __restrict__ OL, float* __restrict__ out){
  int o = threadIdx.x;
  float acc=0.f;
  for(int h=0;h<HD;h++) acc += s0[h]*OL[h*HD+o] + s1[h]*OL[HD*HD + h*HD+o];
  out[o] = acc;
}

extern "C" void kernel_launch(void* const* d_in, const int* in_sizes, int n_in,
                              void* d_out, int out_size, void* d_ws, size_t ws_size,
                              hipStream_t stream) {
  const float* x     = (const float*)d_in[0];
  const float* rbf   = (const float*)d_in[1];
  const float* sbf   = (const float*)d_in[2];
  const int*   nid   = (const int*)d_in[3];
  const int*   ikj   = (const int*)d_in[4];
  const int*   iji   = (const int*)d_in[5];
  const float* W_rbf = (const float*)d_in[6];
  const float* W_sbf = (const float*)d_in[7];
  const float* W_kj  = (const float*)d_in[8];
  const float* b_kj  = (const float*)d_in[9];
  const float* W_ji  = (const float*)d_in[10];
  const float* b_ji  = (const float*)d_in[11];
  const float* W_bil = (const float*)d_in[12];
  const float* W_lin = (const float*)d_in[13];
  const float* b_lin = (const float*)d_in[14];
  const float* olrbf = (const float*)d_in[15];
  const float* olW   = (const float*)d_in[16];
  const float* olb   = (const float*)d_in[17];
  const float* olin  = (const float*)d_in[18];
  float* out = (float*)d_out;

  size_t off = 0;
  auto alloc = [&](size_t bytes)->size_t{ size_t r = off; off = (off + bytes + 255) & ~(size_t)255; return r; };
  size_t o_xkj  = alloc((size_t)NE*HD*2);
  size_t o_agg  = alloc((size_t)NE*HD*4);
  size_t o_wb2  = alloc((size_t)NBB*HD*HD*2);
  size_t o_wkjT = alloc((size_t)HD*HD*2);
  size_t o_wjiT = alloc((size_t)HD*HD*2);
  size_t o_wlinT= alloc((size_t)HD*HD*2);
  size_t o_g0   = alloc((size_t)NN*HD*4);
  size_t o_g1   = alloc((size_t)NN*HD*4);
  size_t o_gt   = alloc((size_t)NN*HD*4);
  size_t o_s0   = alloc(512);
  size_t o_s1   = alloc(512);
  if (off > ws_size) return;
  char* ws = (char*)d_ws;
  __half* xkj  = (__half*)(ws + o_xkj);
  float* agg   = (float*)(ws + o_agg);
  __half* wb2  = (__half*)(ws + o_wb2);
  __half* wkjT = (__half*)(ws + o_wkjT);
  __half* wjiT = (__half*)(ws + o_wjiT);
  __half* wlinT= (__half*)(ws + o_wlinT);
  float* g0    = (float*)(ws + o_g0);
  float* g1    = (float*)(ws + o_g1);
  float* gt    = (float*)(ws + o_gt);
  float* s0    = (float*)(ws + o_s0);
  float* s1    = (float*)(ws + o_s1);

  const int SH_MLP = 65536 + 8192;
  hipFuncSetAttribute((const void*)k_edge_pre,     hipFuncAttributeMaxDynamicSharedMemorySize, SH_PRE);
  hipFuncSetAttribute((const void*)k_edge_post,    hipFuncAttributeMaxDynamicSharedMemorySize, SH_POST);
  hipFuncSetAttribute((const void*)k_triplet_mfma, hipFuncAttributeMaxDynamicSharedMemorySize, SH_TRIP);
  hipFuncSetAttribute((const void*)k_mlp,          hipFuncAttributeMaxDynamicSharedMemorySize, SH_MLP);

  hipMemsetAsync(agg, 0, (size_t)NE*HD*4, stream);
  hipMemsetAsync(g0,  0, (size_t)NN*HD*4, stream);
  hipMemsetAsync(g1,  0, (size_t)NN*HD*4, stream);
  hipMemsetAsync(s0,  0, 512, stream);
  hipMemsetAsync(s1,  0, 512, stream);

  k_wb2<<<512,256,0,stream>>>(W_bil, wb2);
  k_wT<<<192,256,0,stream>>>(W_kj, W_ji, W_lin, wkjT, wjiT, wlinT);

  // ---- interaction + both gate scatters ----
  k_edge_pre<<<(NE+EROWS-1)/EROWS,256,SH_PRE,stream>>>(x, rbf, nid, wkjT, b_kj, W_rbf,
                                                       olrbf, xkj, g0);
  k_triplet_mfma<<<(NT+TROWS-1)/TROWS,256,SH_TRIP,stream>>>(xkj, sbf, W_sbf, ikj, iji, wb2, agg);
  k_edge_post<<<(NE+EROWS-1)/EROWS,256,SH_POST,stream>>>(x, rbf, agg, nid, wjiT, b_ji,
                                                         wlinT, b_lin, olrbf + NRR*HD, g1);

  // ---- output block 0 MLP chain ----
  k_mlp<<<NN/32,256,SH_MLP,stream>>>(g0, olW + 0*16384, olb + 0*128, gt);
  k_mlp<<<NN/32,256,SH_MLP,stream>>>(gt, olW + 1*16384, olb + 1*128, g0);
  k_mlp<<<NN/32,256,SH_MLP,stream>>>(g0, olW + 2*16384, olb + 2*128, gt);
  k_colsum<<<256,256,0,stream>>>(gt, s0);

  // ---- output block 1 MLP chain ----
  k_mlp<<<NN/32,256,SH_MLP,stream>>>(g1, olW + 3*16384, olb + 3*128, gt);
  k_mlp<<<NN/32,256,SH_MLP,stream>>>(gt, olW + 4*16384, olb + 4*128, g1);
  k_mlp<<<NN/32,256,SH_MLP,stream>>>(g1, olW + 5*16384, olb + 5*128, gt);
  k_colsum<<<256,256,0,stream>>>(gt, s1);

  k_readout<<<1,128,0,stream>>>(s0, s1, olin, out);
}

// Round 5
// 1093.202 us; speedup vs baseline: 1.8770x; 1.8770x over previous
//
#include <hip/hip_runtime.h>
#include <hip/hip_fp16.h>

#define NN 20000
#define NE 300000
#define NT 500000
#define HD 128
#define NRR 6
#define NSNRD 42
#define NBB 8

using f16x8 = __attribute__((ext_vector_type(8))) _Float16;
using f32x4 = __attribute__((ext_vector_type(4))) float;

__device__ __forceinline__ float silu_f(float v){ return v / (1.f + __expf(-v)); }

// ---- W_bil [i][jb][l] -> WB2 fp16 [jb][i][l]  (B^T layout for MFMA frags) ----
__global__ void k_wb2(const float* __restrict__ Wb, __half* __restrict__ WB2){
  int idx = blockIdx.x*256 + threadIdx.x;     // 131072 total
  int l = idx & 127, i = (idx>>7) & 127, jb = idx>>14;
  WB2[jb*16384 + i*128 + l] = __float2half(Wb[i*1024 + jb*128 + l]);
}

// ---- W_kj/W_ji/W_lin [k][i] -> fp16 transposed [i][k] ----
__global__ void k_wT(const float* __restrict__ Wkj, const float* __restrict__ Wji,
                     const float* __restrict__ Wlin, __half* __restrict__ WkjT,
                     __half* __restrict__ WjiT, __half* __restrict__ WlinT){
  int idx = blockIdx.x*256 + threadIdx.x;     // 49152 total
  int which = idx>>14, rem = idx & 16383;
  int i = rem>>7, k = rem & 127;
  const float* src = which==0 ? Wkj : (which==1 ? Wji : Wlin);
  __half* dst = which==0 ? WkjT : (which==1 ? WjiT : WlinT);
  dst[rem] = __float2half(src[k*HD + i]);
}

// ---- olW [6][k][i] -> fp16 transposed [6][i][k] ----
__global__ void k_wT6(const float* __restrict__ olW, __half* __restrict__ dst){
  int idx = blockIdx.x*256 + threadIdx.x;     // 98304 total
  int lw = idx>>14, rem = idx & 16383;
  int i = rem>>7, k = rem & 127;
  dst[lw*16384 + rem] = __float2half(olW[lw*16384 + k*HD + i]);
}

// ================= k_edge_pre =================
// xkj = fp16( silu(x@W_kj+b_kj) * (rbf@W_rbf) ), fused block-0 gate scatter.
#define EROWS 128
#define PRE_A 0
#define PRE_B 32768
#define PRE_RBF 65536
#define PRE_WR 68608
#define PRE_LS 71680
#define PRE_NID 74752
#define SH_PRE 75264
__global__ __launch_bounds__(256,2)
void k_edge_pre(const float* __restrict__ x, const float* __restrict__ rbf,
                const int* __restrict__ nid, const __half* __restrict__ WkjT,
                const float* __restrict__ bkj, const float* __restrict__ Wrbf,
                const float* __restrict__ lrbf0, __half* __restrict__ xkj,
                float* __restrict__ g0){
  extern __shared__ char sm[];
  int tid = threadIdx.x;
  long e0 = (long)blockIdx.x * EROWS;
  for(int c=tid;c<2048;c+=256){
    int i=c>>4, cc=c&15;
    float4 v = *(const float4*)(WkjT + i*128 + cc*8);
    *(float4*)(sm + PRE_B + ((i*256+cc*16)^((i&7)<<4))) = v;
  }
  for(int c=tid;c<2048;c+=256){
    int r=c>>4, cc=c&15; long e=e0+r;
    __half h8[8];
    if(e<NE){
      const float* px = x + e*HD + cc*8;
      #pragma unroll
      for(int j=0;j<8;j++) h8[j]=__float2half(px[j]);
    } else {
      #pragma unroll
      for(int j=0;j<8;j++) h8[j]=__float2half(0.f);
    }
    *(float4*)(sm + PRE_A + ((r*256+cc*16)^((r&7)<<4))) = *(float4*)h8;
  }
  float* rbft=(float*)(sm+PRE_RBF);
  for(int q=tid;q<EROWS*NRR;q+=256){ long e=e0+q/NRR; rbft[q]=(e<NE)? rbf[e*NRR + q%NRR] : 0.f; }
  float* wrbf=(float*)(sm+PRE_WR);
  for(int q=tid;q<NRR*HD;q+=256) wrbf[q]=Wrbf[q];
  float* ls0=(float*)(sm+PRE_LS);
  for(int q=tid;q<NRR*HD;q+=256) ls0[q]=lrbf0[q];
  int* nids=(int*)(sm+PRE_NID);
  for(int q=tid;q<EROWS;q+=256){ long e=e0+q; nids[q]=(e<NE)? nid[q-tid+tid+e0<0?0:(int)(e-e0)] : 0; }
  // (simplified below; keep straightforward:)
  __syncthreads();
  if (tid < EROWS){ long e=e0+tid; nids[tid]=(e<NE)? nid[e] : 0; }
  __syncthreads();
  int lane=tid&63, wv=tid>>6;
  f16x8 af[2][4];
  #pragma unroll
  for(int rt=0;rt<2;rt++){
    int r = wv*32 + rt*16 + (lane&15);
    #pragma unroll
    for(int ks=0;ks<4;ks++)
      af[rt][ks] = *(const f16x8*)(sm + PRE_A + ((r*256 + (ks*4+(lane>>4))*16)^((r&7)<<4)));
  }
  f32x4 acc[2][8];
  #pragma unroll
  for(int rt=0;rt<2;rt++){
    #pragma unroll
    for(int ct=0;ct<8;ct++) acc[rt][ct]=(f32x4){0.f,0.f,0.f,0.f};
  }
  #pragma unroll
  for(int ct=0;ct<8;ct++){
    int i = ct*16 + (lane&15);
    #pragma unroll
    for(int ks=0;ks<4;ks++){
      f16x8 b = *(const f16x8*)(sm + PRE_B + ((i*256 + (ks*4+(lane>>4))*16)^((i&7)<<4)));
      acc[0][ct] = __builtin_amdgcn_mfma_f32_16x16x32_f16(af[0][ks], b, acc[0][ct], 0,0,0);
      acc[1][ct] = __builtin_amdgcn_mfma_f32_16x16x32_f16(af[1][ks], b, acc[1][ct], 0,0,0);
    }
  }
  #pragma unroll
  for(int rt=0;rt<2;rt++){
    #pragma unroll
    for(int j=0;j<4;j++){
      int rloc = wv*32 + rt*16 + (lane>>4)*4 + j;
      long e = e0 + rloc;
      if(e<NE){
        #pragma unroll
        for(int ct=0;ct<8;ct++){
          int h = ct*16 + (lane&15);
          float v = silu_f(acc[rt][ct][j] + bkj[h]);
          float r2 = 0.f;
          #pragma unroll
          for(int q=0;q<NRR;q++) r2 += rbft[rloc*NRR+q]*wrbf[q*HD+h];
          xkj[e*HD + h] = __float2half(v*r2);
        }
      }
    }
  }
  // block-0 gate scatter, COALESCED: h = ct*16+(lane&15) -> 16 consecutive 4B atomics
  #pragma unroll
  for(int rt=0;rt<2;rt++){
    #pragma unroll
    for(int j=0;j<4;j++){
      int rloc = wv*32 + rt*16 + (lane>>4)*4 + j;
      long e = e0 + rloc;
      if(e<NE){
        int nb = nids[rloc];
        #pragma unroll
        for(int ct=0;ct<8;ct++){
          int h = ct*16 + (lane&15);
          float xv = __half2float(*(const __half*)(sm + PRE_A +
                        ((rloc*256 + (h>>3)*16)^((rloc&7)<<4)) + (h&7)*2));
          float gate = 0.f;
          #pragma unroll
          for(int q=0;q<NRR;q++) gate += rbft[rloc*NRR+q]*ls0[q*HD+h];
          atomicAdd(&g0[(long)nb*HD + h], gate*xv);
        }
      }
    }
  }
}

// ================= k_triplet_mfma =================
#define TROWS 128
#define OFF_BS 0
#define OFF_XG 32768
#define OFF_SP 65536
#define OFF_JI 69632
#define OFF_KJ 70144
#define OFF_WSB 70656
#define SH_TRIP 72000
__global__ __launch_bounds__(256,2)
void k_triplet_mfma(const __half* __restrict__ xkj, const float* __restrict__ sbf,
                    const float* __restrict__ Wsbf,
                    const int* __restrict__ ikj, const int* __restrict__ iji,
                    const __half* __restrict__ WB2, float* __restrict__ agg){
  extern __shared__ char sm[];
  int tid = threadIdx.x;
  long t0 = (long)blockIdx.x * TROWS;
  int* kjs = (int*)(sm + OFF_KJ);
  int* jis = (int*)(sm + OFF_JI);
  if (tid < TROWS){
    int ok = (t0 + tid) < NT;
    kjs[tid] = ok ? ikj[t0+tid] : 0;
    jis[tid] = ok ? iji[t0+tid] : -1;
  }
  float* sbuf = (float*)(sm + OFF_BS);
  for(int q=tid;q<TROWS*NSNRD;q+=256){
    long t = t0 + q/NSNRD;
    sbuf[q] = (t<NT) ? sbf[t*NSNRD + q%NSNRD] : 0.f;
  }
  float* wsb = (float*)(sm + OFF_WSB);
  for(int q=tid;q<NSNRD*NBB;q+=256) wsb[q]=Wsbf[q];
  __syncthreads();
  for(int c=tid;c<TROWS*16;c+=256){
    int w = c>>4, cc = c&15;
    float4 v = *(const float4*)(xkj + (long)kjs[w]*HD + cc*8);
    *(float4*)(sm + OFF_XG + ((w*256 + cc*16)^((w&7)<<4))) = v;
  }
  float* spl = (float*)(sm + OFF_SP);
  {
    int r = tid>>1, j0 = (tid&1)*4;
    float a0=0.f,a1=0.f,a2=0.f,a3=0.f;
    for(int q=0;q<NSNRD;q++){
      float v = sbuf[r*NSNRD+q];
      a0 += v*wsb[q*NBB+j0];   a1 += v*wsb[q*NBB+j0+1];
      a2 += v*wsb[q*NBB+j0+2]; a3 += v*wsb[q*NBB+j0+3];
    }
    spl[r*NBB+j0]=a0; spl[r*NBB+j0+1]=a1; spl[r*NBB+j0+2]=a2; spl[r*NBB+j0+3]=a3;
  }
  __syncthreads();
  int lane = tid & 63, wvid = tid >> 6;
  float spreg[2][NBB];
  #pragma unroll
  for(int rt=0;rt<2;rt++){
    int w = wvid*32 + rt*16 + (lane&15);
    #pragma unroll
    for(int jb=0;jb<NBB;jb++) spreg[rt][jb] = spl[w*NBB + jb];
  }
  f16x8 au[2][4];
  #pragma unroll
  for(int rt=0;rt<2;rt++){
    int w = wvid*32 + rt*16 + (lane&15);
    #pragma unroll
    for(int ks=0;ks<4;ks++)
      au[rt][ks] = *(const f16x8*)(sm + OFF_XG + ((w*256 + ks*64 + (lane>>4)*16)^((w&7)<<4)));
  }
  f32x4 acc[2][8];
  #pragma unroll
  for(int rt=0;rt<2;rt++){
    #pragma unroll
    for(int ct=0;ct<8;ct++) acc[rt][ct] = (f32x4){0.f,0.f,0.f,0.f};
  }
  for(int jb=0;jb<NBB;jb++){
    __syncthreads();
    for(int c=tid;c<2048;c+=256){
      int i = c>>4, lc = c&15;
      float4 v = *(const float4*)(WB2 + jb*16384 + i*128 + lc*8);
      *(float4*)(sm + OFF_BS + ((i*256 + lc*16)^((i&7)<<4))) = v;
    }
    __syncthreads();
    f16x8 as[2][4];
    #pragma unroll
    for(int rt=0;rt<2;rt++){
      _Float16 s = (_Float16)spreg[rt][jb];
      #pragma unroll
      for(int ks=0;ks<4;ks++){
        #pragma unroll
        for(int j=0;j<8;j++) as[rt][ks][j] = au[rt][ks][j] * s;
      }
    }
    #pragma unroll
    for(int ct=0;ct<8;ct++){
      int i = ct*16 + (lane&15);
      int obase = i*256 + (lane>>4)*16;
      #pragma unroll
      for(int ks=0;ks<4;ks++){
        f16x8 b = *(const f16x8*)(sm + OFF_BS + ((obase + ks*64)^((i&7)<<4)));
        acc[0][ct] = __builtin_amdgcn_mfma_f32_16x16x32_f16(as[0][ks], b, acc[0][ct], 0,0,0);
        acc[1][ct] = __builtin_amdgcn_mfma_f32_16x16x32_f16(as[1][ks], b, acc[1][ct], 0,0,0);
      }
    }
  }
  #pragma unroll
  for(int rt=0;rt<2;rt++){
    #pragma unroll
    for(int r=0;r<4;r++){
      int w = wvid*32 + rt*16 + (lane>>4)*4 + r;
      int ji = jis[w];
      if (ji >= 0){
        #pragma unroll
        for(int ct=0;ct<8;ct++)
          atomicAdd(&agg[(long)ji*HD + ct*16 + (lane&15)], acc[rt][ct][r]);
      }
    }
  }
}

// ================= k_edge_post =================
#define PO_A 0
#define PO_B 32768
#define PO_RBF 65536
#define PO_LS 68608
#define PO_NID 71680
#define SH_POST 72192
__global__ __launch_bounds__(256,2)
void k_edge_post(const float* __restrict__ x, const float* __restrict__ rbf,
                 const float* __restrict__ agg, const int* __restrict__ nid,
                 const __half* __restrict__ WjiT, const float* __restrict__ bji,
                 const __half* __restrict__ WlinT, const float* __restrict__ blin,
                 const float* __restrict__ lrbf1, float* __restrict__ g1){
  extern __shared__ char sm[];
  int tid = threadIdx.x;
  long e0 = (long)blockIdx.x * EROWS;
  for(int c=tid;c<2048;c+=256){
    int i=c>>4, cc=c&15;
    float4 v = *(const float4*)(WjiT + i*128 + cc*8);
    *(float4*)(sm + PO_B + ((i*256+cc*16)^((i&7)<<4))) = v;
  }
  for(int c=tid;c<2048;c+=256){
    int r=c>>4, cc=c&15; long e=e0+r;
    __half h8[8];
    if(e<NE){
      const float* px = x + e*HD + cc*8;
      #pragma unroll
      for(int j=0;j<8;j++) h8[j]=__float2half(px[j]);
    } else {
      #pragma unroll
      for(int j=0;j<8;j++) h8[j]=__float2half(0.f);
    }
    *(float4*)(sm + PO_A + ((r*256+cc*16)^((r&7)<<4))) = *(float4*)h8;
  }
  float* rbft=(float*)(sm+PO_RBF);
  for(int q=tid;q<EROWS*NRR;q+=256){ long e=e0+q/NRR; rbft[q]=(e<NE)? rbf[e*NRR + q%NRR] : 0.f; }
  float* ls1=(float*)(sm+PO_LS);
  for(int q=tid;q<NRR*HD;q+=256) ls1[q]=lrbf1[q];
  int* nids=(int*)(sm+PO_NID);
  if (tid < EROWS){ long e=e0+tid; nids[tid]=(e<NE)? nid[e] : 0; }
  __syncthreads();
  int lane=tid&63, wv=tid>>6;
  f16x8 af[2][4];
  #pragma unroll
  for(int rt=0;rt<2;rt++){
    int r = wv*32 + rt*16 + (lane&15);
    #pragma unroll
    for(int ks=0;ks<4;ks++)
      af[rt][ks] = *(const f16x8*)(sm + PO_A + ((r*256 + (ks*4+(lane>>4))*16)^((r&7)<<4)));
  }
  f32x4 acc[2][8];
  #pragma unroll
  for(int rt=0;rt<2;rt++){
    #pragma unroll
    for(int ct=0;ct<8;ct++) acc[rt][ct]=(f32x4){0.f,0.f,0.f,0.f};
  }
  #pragma unroll
  for(int ct=0;ct<8;ct++){
    int i = ct*16 + (lane&15);
    #pragma unroll
    for(int ks=0;ks<4;ks++){
      f16x8 b = *(const f16x8*)(sm + PO_B + ((i*256 + (ks*4+(lane>>4))*16)^((i&7)<<4)));
      acc[0][ct] = __builtin_amdgcn_mfma_f32_16x16x32_f16(af[0][ks], b, acc[0][ct], 0,0,0);
      acc[1][ct] = __builtin_amdgcn_mfma_f32_16x16x32_f16(af[1][ks], b, acc[1][ct], 0,0,0);
    }
  }
  __syncthreads();
  #pragma unroll
  for(int rt=0;rt<2;rt++){
    #pragma unroll
    for(int j=0;j<4;j++){
      int rloc = wv*32 + rt*16 + (lane>>4)*4 + j;
      long e = e0 + rloc;
      #pragma unroll
      for(int ct=0;ct<8;ct++){
        int h = ct*16 + (lane&15);
        float v = silu_f(acc[rt][ct][j] + bji[h]);
        v += (e<NE) ? agg[e*HD + h] : 0.f;
        int byo = ((rloc*256 + (h>>3)*16)^((rloc&7)<<4)) + (h&7)*2;
        *(__half*)(sm + PO_A + byo) = __float2half(v);
      }
    }
  }
  for(int c=tid;c<2048;c+=256){
    int i=c>>4, cc=c&15;
    float4 v = *(const float4*)(WlinT + i*128 + cc*8);
    *(float4*)(sm + PO_B + ((i*256+cc*16)^((i&7)<<4))) = v;
  }
  __syncthreads();
  f16x8 af2[2][4];
  #pragma unroll
  for(int rt=0;rt<2;rt++){
    int r = wv*32 + rt*16 + (lane&15);
    #pragma unroll
    for(int ks=0;ks<4;ks++)
      af2[rt][ks] = *(const f16x8*)(sm + PO_A + ((r*256 + (ks*4+(lane>>4))*16)^((r&7)<<4)));
  }
  f32x4 acc2[2][8];
  #pragma unroll
  for(int rt=0;rt<2;rt++){
    #pragma unroll
    for(int ct=0;ct<8;ct++) acc2[rt][ct]=(f32x4){0.f,0.f,0.f,0.f};
  }
  #pragma unroll
  for(int ct=0;ct<8;ct++){
    int i = ct*16 + (lane&15);
    #pragma unroll
    for(int ks=0;ks<4;ks++){
      f16x8 b = *(const f16x8*)(sm + PO_B + ((i*256 + (ks*4+(lane>>4))*16)^((i&7)<<4)));
      acc2[0][ct] = __builtin_amdgcn_mfma_f32_16x16x32_f16(af2[0][ks], b, acc2[0][ct], 0,0,0);
      acc2[1][ct] = __builtin_amdgcn_mfma_f32_16x16x32_f16(af2[1][ks], b, acc2[1][ct], 0,0,0);
    }
  }
  #pragma unroll
  for(int rt=0;rt<2;rt++){
    #pragma unroll
    for(int j=0;j<4;j++){
      int rloc = wv*32 + rt*16 + (lane>>4)*4 + j;
      long e = e0 + rloc;
      if(e<NE){
        int nb = nids[rloc];
        #pragma unroll
        for(int ct=0;ct<8;ct++){
          int h = ct*16 + (lane&15);
          float x2 = silu_f(acc2[rt][ct][j] + blin[h]);
          float gate = 0.f;
          #pragma unroll
          for(int q=0;q<NRR;q++) gate += rbft[rloc*NRR+q]*ls1[q*HD+h];
          atomicAdd(&g1[(long)nb*HD + h], gate*x2);
        }
      }
    }
  }
}

// ================= k_mlp_mfma =================
// gout = silu(gin @ W + b), 128 node-rows per block, W pre-transposed fp16 [i][k].
#define SH_MLPM 65536
__global__ __launch_bounds__(256,2)
void k_mlp_mfma(const float* __restrict__ gin, const __half* __restrict__ WT,
                const float* __restrict__ b, float* __restrict__ gout){
  extern __shared__ char sm[];
  int tid = threadIdx.x;
  long r0 = (long)blockIdx.x * EROWS;
  for(int c=tid;c<2048;c+=256){
    int i=c>>4, cc=c&15;
    float4 v = *(const float4*)(WT + i*128 + cc*8);
    *(float4*)(sm + 32768 + ((i*256+cc*16)^((i&7)<<4))) = v;
  }
  for(int c=tid;c<2048;c+=256){
    int r=c>>4, cc=c&15; long rr=r0+r;
    __half h8[8];
    if(rr<NN){
      const float* p = gin + rr*HD + cc*8;
      #pragma unroll
      for(int j=0;j<8;j++) h8[j]=__float2half(p[j]);
    } else {
      #pragma unroll
      for(int j=0;j<8;j++) h8[j]=__float2half(0.f);
    }
    *(float4*)(sm + ((r*256+cc*16)^((r&7)<<4))) = *(float4*)h8;
  }
  __syncthreads();
  int lane=tid&63, wv=tid>>6;
  f16x8 af[2][4];
  #pragma unroll
  for(int rt=0;rt<2;rt++){
    int r = wv*32 + rt*16 + (lane&15);
    #pragma unroll
    for(int ks=0;ks<4;ks++)
      af[rt][ks] = *(const f16x8*)(sm + ((r*256 + (ks*4+(lane>>4))*16)^((r&7)<<4)));
  }
  f32x4 acc[2][8];
  #pragma unroll
  for(int rt=0;rt<2;rt++){
    #pragma unroll
    for(int ct=0;ct<8;ct++) acc[rt][ct]=(f32x4){0.f,0.f,0.f,0.f};
  }
  #pragma unroll
  for(int ct=0;ct<8;ct++){
    int i = ct*16 + (lane&15);
    #pragma unroll
    for(int ks=0;ks<4;ks++){
      f16x8 bfr = *(const f16x8*)(sm + 32768 + ((i*256 + (ks*4+(lane>>4))*16)^((i&7)<<4)));
      acc[0][ct] = __builtin_amdgcn_mfma_f32_16x16x32_f16(af[0][ks], bfr, acc[0][ct], 0,0,0);
      acc[1][ct] = __builtin_amdgcn_mfma_f32_16x16x32_f16(af[1][ks], bfr, acc[1][ct], 0,0,0);
    }
  }
  #pragma unroll
  for(int rt=0;rt<2;rt++){
    #pragma unroll
    for(int j=0;j<4;j++){
      int rloc = wv*32 + rt*16 + (lane>>4)*4 + j;
      long rr = r0 + rloc;
      if(rr<NN){
        #pragma unroll
        for(int ct=0;ct<8;ct++){
          int h = ct*16 + (lane&15);
          gout[rr*HD + h] = silu_f(acc[rt][ct][j] + b[h]);
        }
      }
    }
  }
}

// ---- column-sum over nodes ----
__global__ void k_colsum(const float* __restrict__ gin, float* __restrict__ s){
  int tid=threadIdx.x; int h=tid&127;
  float acc=0.f;
  for(int r = blockIdx.x*2 + (tid>>7); r < NN; r += 512) acc += gin[(long)r*HD + h];
  atomicAdd(&s[h], acc);
}

// ---- final readout ----
__global__ void k_readout(const float* __restrict__ s0, const float* __restrict__ s1,
                          const float* __restrict__ OL, float* __restrict__ out){
  int o = threadIdx.x;
  float acc=0.f;
  for(int h=0;h<HD;h++) acc += s0[h]*OL[h*HD+o] + s1[h]*OL[HD*HD + h*HD+o];
  out[o] = acc;
}

extern "C" void kernel_launch(void* const* d_in, const int* in_sizes, int n_in,
                              void* d_out, int out_size, void* d_ws, size_t ws_size,
                              hipStream_t stream) {
  const float* x     = (const float*)d_in[0];
  const float* rbf   = (const float*)d_in[1];
  const float* sbf   = (const float*)d_in[2];
  const int*   nid   = (const int*)d_in[3];
  const int*   ikj   = (const int*)d_in[4];
  const int*   iji   = (const int*)d_in[5];
  const float* W_rbf = (const float*)d_in[6];
  const float* W_sbf = (const float*)d_in[7];
  const float* W_kj  = (const float*)d_in[8];
  const float* b_kj  = (const float*)d_in[9];
  const float* W_ji  = (const float*)d_in[10];
  const float* b_ji  = (const float*)d_in[11];
  const float* W_bil = (const float*)d_in[12];
  const float* W_lin = (const float*)d_in[13];
  const float* b_lin = (const float*)d_in[14];
  const float* olrbf = (const float*)d_in[15];
  const float* olW   = (const float*)d_in[16];
  const float* olb   = (const float*)d_in[17];
  const float* olin  = (const float*)d_in[18];
  float* out = (float*)d_out;

  size_t off = 0;
  auto alloc = [&](size_t bytes)->size_t{ size_t r = off; off = (off + bytes + 255) & ~(size_t)255; return r; };
  size_t o_xkj  = alloc((size_t)NE*HD*2);
  size_t o_agg  = alloc((size_t)NE*HD*4);
  size_t o_wb2  = alloc((size_t)NBB*HD*HD*2);
  size_t o_wkjT = alloc((size_t)HD*HD*2);
  size_t o_wjiT = alloc((size_t)HD*HD*2);
  size_t o_wlinT= alloc((size_t)HD*HD*2);
  size_t o_wo6  = alloc((size_t)6*HD*HD*2);
  size_t o_g0   = alloc((size_t)NN*HD*4);
  size_t o_g1   = alloc((size_t)NN*HD*4);
  size_t o_gt   = alloc((size_t)NN*HD*4);
  size_t o_s0   = alloc(512);
  size_t o_s1   = alloc(512);
  if (off > ws_size) return;
  char* ws = (char*)d_ws;
  __half* xkj  = (__half*)(ws + o_xkj);
  float* agg   = (float*)(ws + o_agg);
  __half* wb2  = (__half*)(ws + o_wb2);
  __half* wkjT = (__half*)(ws + o_wkjT);
  __half* wjiT = (__half*)(ws + o_wjiT);
  __half* wlinT= (__half*)(ws + o_wlinT);
  __half* wo6  = (__half*)(ws + o_wo6);
  float* g0    = (float*)(ws + o_g0);
  float* g1    = (float*)(ws + o_g1);
  float* gt    = (float*)(ws + o_gt);
  float* s0    = (float*)(ws + o_s0);
  float* s1    = (float*)(ws + o_s1);

  hipFuncSetAttribute((const void*)k_edge_pre,     hipFuncAttributeMaxDynamicSharedMemorySize, SH_PRE);
  hipFuncSetAttribute((const void*)k_edge_post,    hipFuncAttributeMaxDynamicSharedMemorySize, SH_POST);
  hipFuncSetAttribute((const void*)k_triplet_mfma, hipFuncAttributeMaxDynamicSharedMemorySize, SH_TRIP);
  hipFuncSetAttribute((const void*)k_mlp_mfma,     hipFuncAttributeMaxDynamicSharedMemorySize, SH_MLPM);

  hipMemsetAsync(agg, 0, (size_t)NE*HD*4, stream);
  hipMemsetAsync(g0,  0, (size_t)NN*HD*4, stream);
  hipMemsetAsync(g1,  0, (size_t)NN*HD*4, stream);
  hipMemsetAsync(s0,  0, 512, stream);
  hipMemsetAsync(s1,  0, 512, stream);

  k_wb2<<<512,256,0,stream>>>(W_bil, wb2);
  k_wT<<<192,256,0,stream>>>(W_kj, W_ji, W_lin, wkjT, wjiT, wlinT);
  k_wT6<<<384,256,0,stream>>>(olW, wo6);

  // ---- interaction + both gate scatters ----
  k_edge_pre<<<(NE+EROWS-1)/EROWS,256,SH_PRE,stream>>>(x, rbf, nid, wkjT, b_kj, W_rbf,
                                                       olrbf, xkj, g0);
  k_triplet_mfma<<<(NT+TROWS-1)/TROWS,256,SH_TRIP,stream>>>(xkj, sbf, W_sbf, ikj, iji, wb2, agg);
  k_edge_post<<<(NE+EROWS-1)/EROWS,256,SH_POST,stream>>>(x, rbf, agg, nid, wjiT, b_ji,
                                                         wlinT, b_lin, olrbf + NRR*HD, g1);

  int mlpg = (NN+EROWS-1)/EROWS;
  // ---- output block 0 MLP chain ----
  k_mlp_mfma<<<mlpg,256,SH_MLPM,stream>>>(g0, wo6 + 0*16384, olb + 0*128, gt);
  k_mlp_mfma<<<mlpg,256,SH_MLPM,stream>>>(gt, wo6 + 1*16384, olb + 1*128, g0);
  k_mlp_mfma<<<mlpg,256,SH_MLPM,stream>>>(g0, wo6 + 2*16384, olb + 2*128, gt);
  k_colsum<<<256,256,0,stream>>>(gt, s0);

  // ---- output block 1 MLP chain ----
  k_mlp_mfma<<<mlpg,256,SH_MLPM,stream>>>(g1, wo6 + 3*16384, olb + 3*128, gt);
  k_mlp_mfma<<<mlpg,256,SH_MLPM,stream>>>(gt, wo6 + 4*16384, olb + 4*128, g1);
  k_mlp_mfma<<<mlpg,256,SH_MLPM,stream>>>(g1, wo6 + 5*16384, olb + 5*128, gt);
  k_colsum<<<256,256,0,stream>>>(gt, s1);

  k_readout<<<1,128,0,stream>>>(s0, s1, olin, out);
}